// Round 5
// baseline (344.942 us; speedup 1.0000x reference)
//
#include <hip/hip_runtime.h>
#include <hip/hip_bf16.h>
#include <math.h>

typedef __bf16 bf16_t;
typedef bf16_t bf16x4 __attribute__((ext_vector_type(4)));
typedef bf16_t bf16x8 __attribute__((ext_vector_type(8)));
typedef float  f32x4  __attribute__((ext_vector_type(4)));

#define SEQ 200
#define DD  64
#define RS  72    // LDS row stride in bf16 (144 B): 16B-aligned b128, 2-way banks free

#define MFMA(a, b, c) __builtin_amdgcn_mfma_f32_16x16x32_bf16((a), (b), (c), 0, 0, 0)

// ---------------- prep kernel: weight fragments (bf16, transposed) + Q ----------------
// Wbc[n][k] = W1b - W1c ; W1dt[n][k] = W1d ; W2t[n][k] = W2^T ; Q[b][n] = b1 + em@(W1a+W1c)
__global__ __launch_bounds__(256) void prep_kernel(
    const float* __restrict__ em, const float* __restrict__ W1,
    const float* __restrict__ b1, const float* __restrict__ W2,
    bf16_t* __restrict__ Wbc, bf16_t* __restrict__ W1dt,
    bf16_t* __restrict__ W2t, float* __restrict__ Q)
{
  const int tid = threadIdx.x;
  if (blockIdx.x == 0) {
    for (int i = tid; i < 64 * 64; i += 256) {
      int n = i >> 6, k = i & 63;
      Wbc[i]  = (bf16_t)(W1[(64 + k) * 64 + n] - W1[(128 + k) * 64 + n]);
      W1dt[i] = (bf16_t)(W1[(192 + k) * 64 + n]);
    }
    for (int i = tid; i < 32 * 64; i += 256) {
      int n = i >> 6, k = i & 63;
      W2t[i] = (bf16_t)(W2[k * 32 + n]);
    }
  } else {
    int b = (blockIdx.x - 1) * 4 + (tid >> 6);
    int n = tid & 63;
    float acc = b1[n];
    for (int d = 0; d < 64; ++d)
      acc += em[(size_t)b * 64 + d] * (W1[d * 64 + n] + W1[(128 + d) * 64 + n]);
    Q[(size_t)b * 64 + n] = acc;
  }
}

// ---------------- main kernel: block per row; wave-private tile fusion ----------------
// Wave w owns tiles t = w, w+4, w+8 (+12 for w=0). Per tile: stage1 MFMA ->
// h1 overwrite of own tile region (no barrier) -> same-wave transpose read ->
// stage2/3 -> online softmax in registers. 2 block barriers total.
__global__ __launch_bounds__(256, 4) void din_kernel(
    const float* __restrict__ em, const float* __restrict__ eu,
    const float* __restrict__ Xu, const float* __restrict__ b2,
    const float* __restrict__ W3, const float* __restrict__ gam,
    const float* __restrict__ bet, const float* __restrict__ mmean,
    const float* __restrict__ mvar, const bf16_t* __restrict__ Wbc,
    const bf16_t* __restrict__ W1dt, const bf16_t* __restrict__ W2t,
    const float* __restrict__ Q, float* __restrict__ out)
{
  __shared__ __align__(16) bf16_t A[208 * RS];       // 29952 B: Xu tiles -> h1
  __shared__ float lam[4][16];                       // per-wave logit scratch
  __shared__ float wavebuf[4][DD];                   // per-wave pooled partials
  __shared__ float mlbuf[4][2];                      // per-wave (m, l)

  const int tid  = threadIdx.x;
  const int wid  = tid >> 6;
  const int lane = tid & 63;
  const int g    = lane >> 4;
  const int l16  = lane & 15;
  const int b    = blockIdx.x;

  // ---- zero pad rows (s = 200..207) ----
  for (int i = tid; i < 8 * DD; i += 256) {
    int r = SEQ + (i >> 6), c = i & 63;
    A[r * RS + c] = (bf16_t)0.f;
  }

  // ---- stage Xu -> LDS bf16, liveness-bounded groups of 4 loads ----
  const float4* Xr = (const float4*)(Xu + (size_t)b * SEQ * DD);
  #pragma unroll 1
  for (int k0 = 0; k0 < 12; k0 += 4) {
    float4 x[4];
    #pragma unroll
    for (int u = 0; u < 4; ++u) x[u] = Xr[tid + 256 * (k0 + u)];
    #pragma unroll
    for (int u = 0; u < 4; ++u) {
      int v = tid + 256 * (k0 + u);
      bf16x4 xa;
      xa[0] = (bf16_t)x[u].x; xa[1] = (bf16_t)x[u].y;
      xa[2] = (bf16_t)x[u].z; xa[3] = (bf16_t)x[u].w;
      *(bf16x4*)&A[(v >> 4) * RS + (v & 15) * 4] = xa;
    }
  }
  if (tid < 128) {                                    // tail: v = 3072 + tid
    float4 x = Xr[3072 + tid];
    int v = 3072 + tid;
    bf16x4 xa;
    xa[0] = (bf16_t)x.x; xa[1] = (bf16_t)x.y;
    xa[2] = (bf16_t)x.z; xa[3] = (bf16_t)x.w;
    *(bf16x4*)&A[(v >> 4) * RS + (v & 15) * 4] = xa;
  }

  // ---- wave-invariant fragments (L1/L2-hot) ----
  const bf16x8* Wbc8  = (const bf16x8*)Wbc;
  const bf16x8* W1dt8 = (const bf16x8*)W1dt;
  const bf16x8* W2t8  = (const bf16x8*)W2t;
  // B' = (W1b - W1c) + diag(em) * W1d for all 4 n-tiles (32 VGPRs)
  bf16x8 bB[4][2];
  {
    float eml[2][8];
    #pragma unroll
    for (int c = 0; c < 2; ++c) {
      float4 e0 = *(const float4*)&em[(size_t)b * DD + 32 * c + 8 * g];
      float4 e1 = *(const float4*)&em[(size_t)b * DD + 32 * c + 8 * g + 4];
      eml[c][0] = e0.x; eml[c][1] = e0.y; eml[c][2] = e0.z; eml[c][3] = e0.w;
      eml[c][4] = e1.x; eml[c][5] = e1.y; eml[c][6] = e1.z; eml[c][7] = e1.w;
    }
    #pragma unroll
    for (int nt = 0; nt < 4; ++nt) {
      int n = nt * 16 + l16;
      #pragma unroll
      for (int c = 0; c < 2; ++c) {
        bf16x8 wbc = Wbc8[n * 8 + 4 * c + g];
        bf16x8 w1d = W1dt8[n * 8 + 4 * c + g];
        #pragma unroll
        for (int j = 0; j < 8; ++j)
          bB[nt][c][j] = (bf16_t)((float)wbc[j] + eml[c][j] * (float)w1d[j]);
      }
    }
  }
  bf16x8 bW2[2][2];
  #pragma unroll
  for (int c = 0; c < 2; ++c)
    #pragma unroll
    for (int u = 0; u < 2; ++u)
      bW2[c][u] = W2t8[(16 * u + l16) * 8 + 4 * c + g];

  float qv[4];
  #pragma unroll
  for (int nt = 0; nt < 4; ++nt) qv[nt] = Q[(size_t)b * DD + nt * 16 + l16];
  const float b2v0 = b2[l16], b2v1 = b2[16 + l16];
  const float w3v0 = W3[l16], w3v1 = W3[16 + l16];

  __syncthreads();  // barrier 1: A staged

  // ---- online softmax state (per wave over its tiles) ----
  float m = -INFINITY, l = 0.f;
  float pacc[16];
  #pragma unroll
  for (int i = 0; i < 16; ++i) pacc[i] = 0.f;

  for (int t = wid; t < 13; t += 4) {
    const int rb = (16 * t + l16) * RS + 8 * g;
    // Xu A-fragments for this tile (kept live for the pooling update)
    bf16x8 xa0 = *(const bf16x8*)&A[rb];        // cols 8g..8g+7
    bf16x8 xa1 = *(const bf16x8*)&A[rb + 32];   // cols 32+8g..

    // stage 1: all 4 n-tiles
    f32x4 a1[4];
    #pragma unroll
    for (int nt = 0; nt < 4; ++nt) {
      f32x4 a = {0.f, 0.f, 0.f, 0.f};
      a = MFMA(xa0, bB[nt][0], a);
      a = MFMA(xa1, bB[nt][1], a);
      a1[nt] = a;
    }
    // h1 = relu(+Q) -> overwrite OWN tile region (C-layout row=4g+r, col=nt*16+l16)
    #pragma unroll
    for (int nt = 0; nt < 4; ++nt)
      #pragma unroll
      for (int r = 0; r < 4; ++r) {
        float v = a1[nt][r] + qv[nt];
        v = v > 0.f ? v : 0.f;
        A[(16 * t + 4 * g + r) * RS + nt * 16 + l16] = (bf16_t)v;
      }

    // stage 2: same-wave transpose read (A-layout), K=64, N=32
    bf16x8 h0  = *(const bf16x8*)&A[rb];
    bf16x8 h1f = *(const bf16x8*)&A[rb + 32];
    f32x4 a20 = {0.f, 0.f, 0.f, 0.f}, a21 = {0.f, 0.f, 0.f, 0.f};
    a20 = MFMA(h0, bW2[0][0], a20);
    a20 = MFMA(h1f, bW2[1][0], a20);
    a21 = MFMA(h0, bW2[0][1], a21);
    a21 = MFMA(h1f, bW2[1][1], a21);

    // stage 3: logits for the 16 rows of this tile
    #pragma unroll
    for (int r = 0; r < 4; ++r) {
      float p0 = fmaxf(a20[r] + b2v0, 0.f) * w3v0;
      float p1 = fmaxf(a21[r] + b2v1, 0.f) * w3v1;
      float pr = p0 + p1;
      pr += __shfl_xor(pr, 1);
      pr += __shfl_xor(pr, 2);
      pr += __shfl_xor(pr, 4);
      pr += __shfl_xor(pr, 8);
      if (l16 == 0) {
        int row = 4 * g + r;
        lam[wid][row] = (16 * t + row < SEQ) ? pr : -INFINITY;
      }
    }
    float lv = lam[wid][l16];          // same-wave DS ordering
    float mt = lv;
    mt = fmaxf(mt, __shfl_xor(mt, 1));
    mt = fmaxf(mt, __shfl_xor(mt, 2));
    mt = fmaxf(mt, __shfl_xor(mt, 4));
    mt = fmaxf(mt, __shfl_xor(mt, 8));

    float mn    = fmaxf(m, mt);
    float alpha = __expf(m - mn);      // first tile: exp(-inf) = 0
    float e     = __expf(lv - mn);     // masked rows: 0
    float es = e;
    es += __shfl_xor(es, 1);
    es += __shfl_xor(es, 2);
    es += __shfl_xor(es, 4);
    es += __shfl_xor(es, 8);
    l = l * alpha + es;
    #pragma unroll
    for (int j = 0; j < 8; ++j) {
      pacc[j]     = pacc[j]     * alpha + e * (float)xa0[j];
      pacc[8 + j] = pacc[8 + j] * alpha + e * (float)xa1[j];
    }
    m = mn;
  }

  // ---- reduce pacc over the 16 row-lanes (shfl butterfly), publish per wave ----
  #pragma unroll
  for (int i = 0; i < 16; ++i) {
    pacc[i] += __shfl_xor(pacc[i], 1);
    pacc[i] += __shfl_xor(pacc[i], 2);
    pacc[i] += __shfl_xor(pacc[i], 4);
    pacc[i] += __shfl_xor(pacc[i], 8);
  }
  if (l16 == 0) {
    #pragma unroll
    for (int j = 0; j < 8; ++j) {
      wavebuf[wid][8 * g + j]      = pacc[j];
      wavebuf[wid][32 + 8 * g + j] = pacc[8 + j];
    }
    if (g == 0) { mlbuf[wid][0] = m; mlbuf[wid][1] = l; }
  }
  __syncthreads();  // barrier 2: all wave partials published

  // ---- cross-wave softmax merge + BN + concat output ----
  if (tid < 192) {
    const size_t ob = (size_t)b * 192;
    float v;
    if (tid < 64) {
      float m0 = mlbuf[0][0], m1 = mlbuf[1][0], m2 = mlbuf[2][0], m3 = mlbuf[3][0];
      float ms = fmaxf(fmaxf(m0, m1), fmaxf(m2, m3));
      float s0 = __expf(m0 - ms), s1 = __expf(m1 - ms);
      float s2 = __expf(m2 - ms), s3 = __expf(m3 - ms);
      float ls = s0 * mlbuf[0][1] + s1 * mlbuf[1][1] +
                 s2 * mlbuf[2][1] + s3 * mlbuf[3][1];
      float num = s0 * wavebuf[0][tid] + s1 * wavebuf[1][tid] +
                  s2 * wavebuf[2][tid] + s3 * wavebuf[3][tid];
      float pooled = num / ls;
      v = (pooled - mmean[tid]) * rsqrtf(mvar[tid] + 1e-3f) * gam[tid] + bet[tid];
    } else if (tid < 128) {
      float x = em[(size_t)b * DD + (tid - 64)];
      v = (x - mmean[tid]) * rsqrtf(mvar[tid] + 1e-3f) * gam[tid] + bet[tid];
    } else {
      v = eu[(size_t)b * DD + (tid - 128)];
    }
    out[ob + tid] = v;
  }
}

extern "C" void kernel_launch(void* const* d_in, const int* in_sizes, int n_in,
                              void* d_out, int out_size, void* d_ws, size_t ws_size,
                              hipStream_t stream) {
  const float* em = (const float*)d_in[0];
  const float* eu = (const float*)d_in[1];
  const float* Xu = (const float*)d_in[2];
  const float* W1 = (const float*)d_in[3];
  const float* b1 = (const float*)d_in[4];
  const float* W2 = (const float*)d_in[5];
  const float* b2 = (const float*)d_in[6];
  const float* W3 = (const float*)d_in[7];
  // b3 dropped: constant logit shift is softmax-invariant
  const float* ga = (const float*)d_in[9];
  const float* be = (const float*)d_in[10];
  const float* mm = (const float*)d_in[11];
  const float* mv = (const float*)d_in[12];
  int B = in_sizes[0] / DD;

  float*  Q    = (float*)d_ws;
  bf16_t* Wbc  = (bf16_t*)((char*)d_ws + (size_t)B * 64 * 4);
  bf16_t* W1dt = Wbc  + 64 * 64;
  bf16_t* W2t  = W1dt + 64 * 64;

  prep_kernel<<<1 + B / 4, 256, 0, stream>>>(em, W1, b1, W2, Wbc, W1dt, W2t, Q);
  din_kernel<<<B, 256, 0, stream>>>(em, eu, Xu, b2, W3, ga, be, mm, mv,
                                    Wbc, W1dt, W2t, Q, (float*)d_out);
}